// Round 11
// baseline (6014.939 us; speedup 1.0000x reference)
//
#include <hip/hip_runtime.h>
#include <cstddef>

// ---------------------------------------------------------------------------
// VGG_DC round 11: R7 base (best, 5.79ms; swizzle reverted) + LDS-input-staged
// tiled convf (convf_t) for L3/L5/L6: tile 16w x 64h per block, input rows
// staged to LDS once per block per ci (6x fewer L1 bytes, 7x fewer VMEM
// requests) -> attacks the ~18% VMEM-stall idle. FMA chains identical to
// R2-R10 -> bit-identical output (absmax 8192).
// ---------------------------------------------------------------------------

typedef float v2f __attribute__((ext_vector_type(2)));

static __device__ __forceinline__ int dot4(int a, int b, int c) {
#if __has_builtin(__builtin_amdgcn_sdot4)
    return __builtin_amdgcn_sdot4(a, b, c, false);
#else
    return c + (a & 255) * (b & 255)
             + ((a >> 8) & 255) * ((b >> 8) & 255)
             + ((a >> 16) & 255) * ((b >> 16) & 255)
             + ((a >> 24) & 255) * ((b >> 24) & 255);
#endif
}

// dual-stream row: a0=[0:1] a1=[2:3] a2=[4:5] (aligned), b0=[1:2] b1=[3:4]
struct Rw { v2f a0, a1, a2, b0, b1; };

static __device__ __forceinline__ Rw ldr(const float* __restrict__ p) {
    Rw r;
    const float4 x = *reinterpret_cast<const float4*>(p);
    const float2 y = *reinterpret_cast<const float2*>(p + 4);
    const float4 z = *reinterpret_cast<const float4*>(p + 1);
    r.a0 = v2f{x.x, x.y}; r.a1 = v2f{x.z, x.w}; r.a2 = v2f{y.x, y.y};
    r.b0 = v2f{z.x, z.y}; r.b1 = v2f{z.z, z.w};
    return r;
}

static __device__ __forceinline__ void ld6i(const int* __restrict__ p, int v[6]) {
    const int4 a = *reinterpret_cast<const int4*>(p);
    const int2 b = *reinterpret_cast<const int2*>(p + 4);
    v[0] = a.x; v[1] = a.y; v[2] = a.z; v[3] = a.w; v[4] = b.x; v[5] = b.y;
}

// 8 co x 4 w FMA block for one input channel (rows v[0..2])
static __device__ __forceinline__ void fmac8(const Rw v[3],
                                             const float* __restrict__ wr,
                                             v2f acc[8][2])
{
#pragma unroll
    for (int kh = 0; kh < 3; ++kh) {
        const Rw r = v[kh];
#pragma unroll
        for (int c = 0; c < 8; ++c) {
            const float k0 = wr[c * 9 + kh * 3 + 0];
            const float k1 = wr[c * 9 + kh * 3 + 1];
            const float k2 = wr[c * 9 + kh * 3 + 2];
            const v2f k0p = {k0, k0}, k1p = {k1, k1}, k2p = {k2, k2};
            v2f a0 = acc[c][0];
            a0 = __builtin_elementwise_fma(r.a1, k2p, a0);   // P2
            a0 = __builtin_elementwise_fma(r.b0, k1p, a0);   // P1
            a0 = __builtin_elementwise_fma(r.a0, k0p, a0);   // P0
            acc[c][0] = a0;
            v2f a1 = acc[c][1];
            a1 = __builtin_elementwise_fma(r.a2, k2p, a1);   // Q2
            a1 = __builtin_elementwise_fma(r.b1, k1p, a1);   // Q1
            a1 = __builtin_elementwise_fma(r.a1, k0p, a1);   // Q0 (=P2)
            acc[c][1] = a1;
        }
    }
}

// convfp FMA block (4 co, 2 pool-rows x 4 w), rows v[0..3]
static __device__ __forceinline__ void fmac4p(const Rw v[4],
                                              const float* __restrict__ wr,
                                              v2f acc[4][2][2])
{
#pragma unroll
    for (int r = 0; r < 2; ++r) {
#pragma unroll
        for (int kh = 0; kh < 3; ++kh) {
            const Rw rv = v[r + kh];
#pragma unroll
            for (int c = 0; c < 4; ++c) {
                const float k0 = wr[c * 9 + kh * 3 + 0];
                const float k1 = wr[c * 9 + kh * 3 + 1];
                const float k2 = wr[c * 9 + kh * 3 + 2];
                const v2f k0p = {k0, k0}, k1p = {k1, k1}, k2p = {k2, k2};
                v2f a0 = acc[c][r][0];
                a0 = __builtin_elementwise_fma(rv.a1, k2p, a0);
                a0 = __builtin_elementwise_fma(rv.b0, k1p, a0);
                a0 = __builtin_elementwise_fma(rv.a0, k0p, a0);
                acc[c][r][0] = a0;
                v2f a1 = acc[c][r][1];
                a1 = __builtin_elementwise_fma(rv.a2, k2p, a1);
                a1 = __builtin_elementwise_fma(rv.b1, k1p, a1);
                a1 = __builtin_elementwise_fma(rv.a1, k0p, a1);
                acc[c][r][1] = a1;
            }
        }
    }
}

// dot4 block for convq (8 co, 4 w)
static __device__ __forceinline__ void dotc8(const int v[3][6],
                                             const int* __restrict__ wr,
                                             int acc[8][4])
{
#pragma unroll
    for (int kh = 0; kh < 3; ++kh) {
#pragma unroll
        for (int c = 0; c < 8; ++c) {
            const int k0 = wr[c * 9 + kh * 3 + 0];
            const int k1 = wr[c * 9 + kh * 3 + 1];
            const int k2 = wr[c * 9 + kh * 3 + 2];
#pragma unroll
            for (int t = 0; t < 4; ++t)
                acc[c][t] = dot4(v[kh][t], k0,
                            dot4(v[kh][t + 1], k1,
                            dot4(v[kh][t + 2], k2, acc[c][t])));
        }
    }
}

// ---- TILED fp32 conv3x3 with LDS input staging ---------------------------
// tile = (4*TWB) w x TH h, 256 threads (tw = tid%TWB, th = tid/TWB).
// grid: x = cob, z = tile (wt fastest, then ht, then n).
template<int CIN,int PH,int PW,int OH,int OW,int OPW,int TWB,int TH,bool BORDER>
__global__ __launch_bounds__(256) void convf_t(
    const float* __restrict__ in, int instr,
    const float* __restrict__ wfp, const float* __restrict__ bias,
    float* __restrict__ out, int outstr)
{
    constexpr int WB   = (OW + 3) / 4;
    constexpr int WT   = (OW + 4 * TWB - 1) / (4 * TWB);
    constexpr int HT   = (OH + TH - 1) / TH;
    constexpr int ROWD = (TWB + 2) * 4;          // LDS row stride (dwords)
    constexpr int RF4  = TWB + 1;                // staged float4 per row
    constexpr int SC   = (TH + 2) * RF4;         // staged float4 count
    constexpr int OPH  = BORDER ? OH + 4 : OH;
    constexpr int OPL  = OPH * OPW;
    __shared__ float lw[(TH + 2) * ROWD];

    const int cob = blockIdx.x;
    const int co0 = cob * 8;
    int tz = blockIdx.z;
    const int wt = tz % WT; tz /= WT;
    const int ht = tz % HT; const int n = tz / HT;
    const int w0t = wt * TWB * 4;
    const int h0  = ht * TH;
    const int tw = threadIdx.x % TWB;
    const int th = threadIdx.x / TWB;

    const float* plane0 = in + (size_t)n * instr + (size_t)h0 * PW + w0t;
    const float* wl = wfp + (size_t)cob * CIN * 72;

    v2f acc[8][2];
#pragma unroll
    for (int c = 0; c < 8; ++c) { acc[c][0] = (v2f)0.f; acc[c][1] = (v2f)0.f; }

    for (int ci = 0; ci < CIN; ++ci) {
        __syncthreads();
        {
            const float4* sp = (const float4*)(plane0 + (size_t)ci * PH * PW);
#pragma unroll
            for (int i0 = 0; i0 < SC; i0 += 256) {
                const int i = i0 + threadIdx.x;
                if (i < SC) {
                    const int r = i / RF4, c = i % RF4;
                    *(float4*)&lw[r * ROWD + 4 * c] = sp[(size_t)r * (PW / 4) + c];
                }
            }
        }
        __syncthreads();
        {
            const float* r0 = lw + th * ROWD + 4 * tw;
            Rw v[3];
#pragma unroll
            for (int kh = 0; kh < 3; ++kh) {
                const float* rp = r0 + kh * ROWD;
                v[kh].a0 = *(const v2f*)(rp);
                v[kh].a1 = *(const v2f*)(rp + 2);
                v[kh].a2 = *(const v2f*)(rp + 4);
                v[kh].b0 = v2f{rp[1], rp[2]};
                v[kh].b1 = v2f{rp[3], rp[4]};
            }
            fmac8(v, wl + (size_t)ci * 72, acc);
        }
    }

    const int h  = h0 + th;
    const int w0 = w0t + 4 * tw;
    if (h < OH) {
        float* ob = out + (size_t)n * outstr;
        const int wb = w0 / 4;
        const int ph  = BORDER ? h + 2 : h;
        const int pwo = BORDER ? 2 : 0;
#pragma unroll
        for (int c = 0; c < 8; ++c) {
            float* plane = ob + (size_t)(co0 + c) * OPL;
            float* row = plane + (size_t)ph * OPW;
            const float b = bias[co0 + c];
            const float av[4] = {acc[c][0][0], acc[c][0][1], acc[c][1][0], acc[c][1][1]};
#pragma unroll
            for (int t = 0; t < 4; ++t)
                if (w0 + t < OW) { const float r = av[t] + b; row[pwo + w0 + t] = r > 0.f ? r : 0.f; }
            if (BORDER) {
                if (wb == 0) { row[0] = 0.f; row[1] = 0.f; }
                if (wb == WB - 1) { for (int pw = OW + 2; pw < OPW; ++pw) row[pw] = 0.f; }
                if (h == 0 || h == OH - 1) {
                    float* r0 = plane + (h == 0 ? 0 : (size_t)(OH + 2) * OPW);
                    for (int rr = 0; rr < 2; ++rr) {
                        float* br = r0 + (size_t)rr * OPW;
#pragma unroll
                        for (int t = 0; t < 4; ++t) if (w0 + t < OW) br[2 + w0 + t] = 0.f;
                        if (wb == 0) { br[0] = 0.f; br[1] = 0.f; }
                        if (wb == WB - 1) { for (int pw = OW + 2; pw < OPW; ++pw) br[pw] = 0.f; }
                    }
                }
            }
        }
    }
}

// ---- direct fp32 conv3x3 (kept for L1, CIN=3) ----------------------------
template<int CIN,int PH,int PW,int OH,int OW,int OPW,bool BORDER>
__global__ __launch_bounds__(256) void convf_k(
    const float* __restrict__ in, int instr,
    const float* __restrict__ wfp, const float* __restrict__ bias,
    float* __restrict__ out, int outstr, int total)
{
    constexpr int WB  = (OW + 3) / 4;
    constexpr int OPH = BORDER ? OH + 4 : OH;
    constexpr int OPL = OPH * OPW;
    const int s = blockIdx.z * 256 + threadIdx.x;
    if (s >= total) return;
    const int wb = s % WB;
    const int h  = (s / WB) % OH;
    const int n  = s / (WB * OH);
    const int w0 = wb * 4;
    const int cob = blockIdx.x;
    const int co0 = cob * 8;

    const float* ip = in + (size_t)n * instr + (size_t)h * PW + w0;
    const float* wl = wfp + (size_t)cob * CIN * 72;

    v2f acc[8][2];
#pragma unroll
    for (int c = 0; c < 8; ++c) { acc[c][0] = (v2f)0.f; acc[c][1] = (v2f)0.f; }

#pragma unroll 1
    for (int ci = 0; ci < CIN; ++ci) {
        Rw v[3];
#pragma unroll
        for (int kh = 0; kh < 3; ++kh) v[kh] = ldr(ip + kh * PW);
        fmac8(v, wl + (size_t)ci * 72, acc);
        ip += PH * PW;
    }

    float* ob = out + (size_t)n * outstr;
    const int ph  = BORDER ? h + 2 : h;
    const int pwo = BORDER ? 2 : 0;
#pragma unroll
    for (int c = 0; c < 8; ++c) {
        float* plane = ob + (size_t)(co0 + c) * OPL;
        float* row = plane + (size_t)ph * OPW;
        const float b = bias[co0 + c];
        const float av[4] = {acc[c][0][0], acc[c][0][1], acc[c][1][0], acc[c][1][1]};
#pragma unroll
        for (int t = 0; t < 4; ++t)
            if (w0 + t < OW) { const float r = av[t] + b; row[pwo + w0 + t] = r > 0.f ? r : 0.f; }
        if (BORDER) {
            if (wb == 0) { row[0] = 0.f; row[1] = 0.f; }
            if (wb == WB - 1) { for (int pw = OW + 2; pw < OPW; ++pw) row[pw] = 0.f; }
            if (h == 0 || h == OH - 1) {
                float* r0 = plane + (h == 0 ? 0 : (size_t)(OH + 2) * OPW);
                for (int rr = 0; rr < 2; ++rr) {
                    float* br = r0 + (size_t)rr * OPW;
#pragma unroll
                    for (int t = 0; t < 4; ++t) if (w0 + t < OW) br[2 + w0 + t] = 0.f;
                    if (wb == 0) { br[0] = 0.f; br[1] = 0.f; }
                    if (wb == WB - 1) { for (int pw = OW + 2; pw < OPW; ++pw) br[pw] = 0.f; }
                }
            }
        }
    }
}

// ---- fused fp32 conv3x3 + relu + maxpool2; MODE 0=float out, 1=packed i8x4
template<int CIN,int PH,int PW,int POH,int POW,int OPW,int OY,int OX,int MODE>
__global__ __launch_bounds__(256) void convfp_k(
    const float* __restrict__ in, int instr,
    const float* __restrict__ wfp, const float* __restrict__ bias,
    void* __restrict__ outv, int outstr, int total)
{
    constexpr int WBp = POW / 2;
    constexpr int OPH = POH + 2 * OY;
    constexpr int OPL = OPH * OPW;
    const int s = blockIdx.z * 256 + threadIdx.x;
    if (s >= total) return;
    const int pb = s % WBp;
    const int ph = (s / WBp) % POH;
    const int n  = s / (WBp * POH);
    const int cob = blockIdx.x;
    const int co0 = cob * 4;

    const float* ip = in + (size_t)n * instr + (size_t)(2 * ph) * PW + 4 * pb;
    const float* wl = wfp + (size_t)cob * CIN * 36;

    v2f acc[4][2][2];
#pragma unroll
    for (int c = 0; c < 4; ++c)
#pragma unroll
        for (int r = 0; r < 2; ++r) { acc[c][r][0] = (v2f)0.f; acc[c][r][1] = (v2f)0.f; }

#pragma unroll 2
    for (int ci = 0; ci < CIN; ++ci) {
        Rw v[4];
#pragma unroll
        for (int r = 0; r < 4; ++r) v[r] = ldr(ip + r * PW);
        fmac4p(v, wl + (size_t)ci * 36, acc);
        ip += PH * PW;
    }

    float p[4][2];
#pragma unroll
    for (int c = 0; c < 4; ++c) {
        const float b = bias[co0 + c];
        float r00 = acc[c][0][0][0] + b; r00 = r00 > 0.f ? r00 : 0.f;
        float r01 = acc[c][0][0][1] + b; r01 = r01 > 0.f ? r01 : 0.f;
        float r02 = acc[c][0][1][0] + b; r02 = r02 > 0.f ? r02 : 0.f;
        float r03 = acc[c][0][1][1] + b; r03 = r03 > 0.f ? r03 : 0.f;
        float r10 = acc[c][1][0][0] + b; r10 = r10 > 0.f ? r10 : 0.f;
        float r11 = acc[c][1][0][1] + b; r11 = r11 > 0.f ? r11 : 0.f;
        float r12 = acc[c][1][1][0] + b; r12 = r12 > 0.f ? r12 : 0.f;
        float r13 = acc[c][1][1][1] + b; r13 = r13 > 0.f ? r13 : 0.f;
        float p0 = r00; p0 = p0 > r01 ? p0 : r01; p0 = p0 > r10 ? p0 : r10; p0 = p0 > r11 ? p0 : r11;
        float p1 = r02; p1 = p1 > r03 ? p1 : r03; p1 = p1 > r12 ? p1 : r12; p1 = p1 > r13 ? p1 : r13;
        p[c][0] = p0; p[c][1] = p1;
    }

    if constexpr (MODE == 1) {
        int* base = (int*)outv + (size_t)n * outstr + (size_t)cob * OPL
                  + (size_t)(OY + ph) * OPW + OX + 2 * pb;
        base[0] = (((int)p[0][0]) & 31) | ((((int)p[1][0]) & 31) << 8)
                | ((((int)p[2][0]) & 31) << 16) | ((((int)p[3][0]) & 31) << 24);
        base[1] = (((int)p[0][1]) & 31) | ((((int)p[1][1]) & 31) << 8)
                | ((((int)p[2][1]) & 31) << 16) | ((((int)p[3][1]) & 31) << 24);
        if (pb == WBp - 1) {
            int* row = (int*)outv + (size_t)n * outstr + (size_t)cob * OPL
                     + (size_t)(OY + ph) * OPW;
            for (int pw = OX + POW; pw < OPW; ++pw) row[pw] = 0;
        }
    } else {
#pragma unroll
        for (int c = 0; c < 4; ++c) {
            float* plane = (float*)outv + (size_t)n * outstr + (size_t)(co0 + c) * OPL;
            float* row = plane + (size_t)(OY + ph) * OPW;
            row[OX + 2 * pb]     = p[c][0];
            row[OX + 2 * pb + 1] = p[c][1];
            if (OX > 0 && pb == 0) { row[0] = 0.f; row[1] = 0.f; }
            if (pb == WBp - 1) { for (int pw = OX + POW; pw < OPW; ++pw) row[pw] = 0.f; }
            if (OY > 0 && (ph == 0 || ph == POH - 1)) {
                float* r0 = plane + (ph == 0 ? 0 : (size_t)(OY + POH) * OPW);
                for (int rr = 0; rr < OY; ++rr) {
                    float* br = r0 + (size_t)rr * OPW;
                    br[OX + 2 * pb] = 0.f; br[OX + 2 * pb + 1] = 0.f;
                    if (pb == 0) { br[0] = 0.f; br[1] = 0.f; }
                    if (pb == WBp - 1) { for (int pw = OX + POW; pw < OPW; ++pw) br[pw] = 0.f; }
                }
            }
        }
    }
}

// ---- int DC conv3x3 (valid) on i8x4-packed input -------------------------
template<int CIN4,int PH,int PW,int OH,int OW,int OPW,bool PACKOUT>
__global__ __launch_bounds__(256) void convq_k(
    const int* __restrict__ in, int instr, const int* __restrict__ wqp,
    int* __restrict__ out, int outstr, int total)
{
    constexpr int WB  = (OW + 3) / 4;
    constexpr int OPL = OH * OPW;
    const int s = blockIdx.z * 256 + threadIdx.x;
    if (s >= total) return;
    const int wb = s % WB;
    const int h  = (s / WB) % OH;
    const int n  = s / (WB * OH);
    const int w0 = wb * 4;
    const int cob = blockIdx.x;
    const int co0 = cob * 8;

    const int* ip = in + (size_t)n * instr + (size_t)h * PW + w0;
    const int* wl = wqp + (size_t)cob * CIN4 * 72;

    int acc[8][4];
#pragma unroll
    for (int c = 0; c < 8; ++c)
#pragma unroll
        for (int t = 0; t < 4; ++t) acc[c][t] = 0;

    int vb[3][6], vn[3][6];
#pragma unroll
    for (int kh = 0; kh < 3; ++kh) ld6i(ip + kh * PW, vb[kh]);

    for (int ci = 0; ci < CIN4; ci += 2) {       // CIN4 even always
        ip += PH * PW;
#pragma unroll
        for (int kh = 0; kh < 3; ++kh) ld6i(ip + kh * PW, vn[kh]);
        dotc8(vb, wl + (size_t)ci * 72, acc);
        ip += PH * PW;                           // final iter overreads 1 plane (guarded)
#pragma unroll
        for (int kh = 0; kh < 3; ++kh) ld6i(ip + kh * PW, vb[kh]);
        dotc8(vn, wl + (size_t)(ci + 1) * 72, acc);
    }

    if (PACKOUT) {
        int* base = out + (size_t)n * outstr + (size_t)(cob * 2) * OPL + (size_t)h * OPW + w0;
#pragma unroll
        for (int t = 0; t < 4; ++t) {
            if (w0 + t < OW) {
                const int lo = (acc[0][t] & 31) | ((acc[1][t] & 31) << 8)
                             | ((acc[2][t] & 31) << 16) | ((acc[3][t] & 31) << 24);
                const int hi = (acc[4][t] & 31) | ((acc[5][t] & 31) << 8)
                             | ((acc[6][t] & 31) << 16) | ((acc[7][t] & 31) << 24);
                base[t] = lo;
                base[OPL + t] = hi;
            }
        }
        if (wb == WB - 1) {
            for (int pw = OW; pw < OPW; ++pw) { base[pw - w0] = 0; base[OPL + pw - w0] = 0; }
        }
    } else {
        int* ob = out + (size_t)n * outstr;
#pragma unroll
        for (int c = 0; c < 8; ++c) {
            int* row = ob + (size_t)(co0 + c) * OPL + (size_t)h * OPW;
#pragma unroll
            for (int t = 0; t < 4; ++t)
                if (w0 + t < OW) row[w0 + t] = acc[c][t];
            if (wb == WB - 1) { for (int pw = OW; pw < OPW; ++pw) row[pw] = 0; }
        }
    }
}

// ---- weight packing ------------------------------------------------------
__global__ void pack_wf_k(const float* __restrict__ w, float* __restrict__ out,
                          int CIN, int TC, int total)
{
    const int i = blockIdx.x * 256 + threadIdx.x;
    if (i >= total) return;
    const int r = i % 9;
    const int c = (i / 9) % TC;
    const int t = i / (9 * TC);
    const int ci = t % CIN;
    const int cob = t / CIN;
    out[i] = w[(((size_t)cob * TC + c) * CIN + ci) * 9 + r];
}

__global__ void pack_wq_k(const int* __restrict__ q, int* __restrict__ out,
                          int CIN4, int total)
{
    const int i = blockIdx.x * 256 + threadIdx.x;
    if (i >= total) return;
    const int r = i % 9;
    const int c = (i / 9) % 8;
    const int t = i / 72;
    const int ci4 = t % CIN4;
    const int cob = t / CIN4;
    const int co = cob * 8 + c;
    const int* p = q + ((size_t)co * CIN4 * 4 + ci4 * 4) * 9 + r;
    out[i] = (p[0] & 255) | ((p[9] & 255) << 8) | ((p[18] & 255) << 16) | ((p[27] & 255) << 24);
}

// ---- fused int maxpool 2x2/2 + mask + i8x4 pack --------------------------
template<int C4,int HI,int WI,int HO,int WO,int OPH,int OPW>
__global__ void poolpack_k(const int* __restrict__ in, int instr,
                           int* __restrict__ out, int outstr, int total)
{
    const int i = blockIdx.x * 256 + threadIdx.x;
    if (i >= total) return;
    int t = i;
    const int px = t % OPW; t /= OPW;
    const int py = t % OPH; t /= OPH;
    const int c4 = t % C4;  const int n = t / C4;
    int word = 0;
    if (py < HO && px < WO) {
#pragma unroll
        for (int j = 0; j < 4; ++j) {
            const int* p = in + (size_t)n * instr
                         + ((size_t)(c4 * 4 + j) * HI + 2 * py) * WI + 2 * px;
            int m = p[0];
            m = m > p[1] ? m : p[1];
            m = m > p[WI] ? m : p[WI];
            m = m > p[WI + 1] ? m : p[WI + 1];
            word |= (m & 31) << (8 * j);
        }
    }
    out[(size_t)n * outstr + ((size_t)c4 * OPH + py) * OPW + px] = word;
}

// ---- int maxpool (raw) ---------------------------------------------------
template<int C,int HI,int WI,int HO,int WO,int OPH,int OPW>
__global__ void pool_i_k(const int* __restrict__ in, int instr,
                         int* __restrict__ out, int outstr, int total)
{
    const int i = blockIdx.x * 256 + threadIdx.x;
    if (i >= total) return;
    constexpr int OPL = OPH * OPW;
    int t = i;
    const int px = t % OPW; t /= OPW;
    const int py = t % OPH; t /= OPH;
    const int c  = t % C;   const int n = t / C;
    int v = 0;
    if (py < HO && px < WO) {
        const int* p = in + (size_t)n * instr + ((size_t)c * HI + 2 * py) * WI + 2 * px;
        int m = p[0];
        m = m > p[1] ? m : p[1];
        m = m > p[WI] ? m : p[WI];
        m = m > p[WI + 1] ? m : p[WI + 1];
        v = m;
    }
    out[(size_t)n * outstr + (size_t)c * OPL + (size_t)py * OPW + px] = v;
}

// ---- copy x into padded (3,228,232) --------------------------------------
__global__ void copyin_k(const float* __restrict__ x, float* __restrict__ dst,
                         int outstr, int total)
{
    const int i = blockIdx.x * 256 + threadIdx.x;
    if (i >= total) return;
    int t = i;
    const int pw = t % 232; t /= 232;
    const int ph = t % 228; t /= 228;
    const int c  = t % 3;   const int n = t / 3;
    float v = 0.f;
    const int y = ph - 2, xx = pw - 2;
    if ((unsigned)y < 224u && (unsigned)xx < 224u)
        v = x[(size_t)n * 150528 + ((size_t)c * 224 + y) * 224 + xx];
    dst[(size_t)n * outstr + ((size_t)c * 228 + ph) * 232 + pw] = v;
}

// ---- head ----------------------------------------------------------------
__global__ void pool_mean_k(const int* __restrict__ in, int instr,
                            float* __restrict__ out, int outstr, int total)
{
    const int i = blockIdx.x * 256 + threadIdx.x;
    if (i >= total) return;
    const int n = i / 512, c = i % 512;
    const int* p = in + (size_t)n * instr + (size_t)c * 33;
    int s = 0;
#pragma unroll
    for (int j = 0; j < 33; ++j) s += p[j];
    out[(size_t)n * outstr + c] = (float)s / 33.0f;
}

__global__ void fc_k(const float* __restrict__ pooled, const float* __restrict__ w,
                     const float* __restrict__ b, float* __restrict__ out,
                     int nb, int n0)
{
    const int i = blockIdx.x * 256 + threadIdx.x;
    if (i >= nb * 1000) return;
    const int co = i % 1000;
    const int n  = i / 1000;
    const float4* pv = (const float4*)(pooled + (size_t)n * 512);
    const float4* wr = (const float4*)(w + (size_t)co * 512);
    float s = b[co];
    for (int c = 0; c < 128; ++c) {
        const float4 a = pv[c], q = wr[c];
        s = fmaf(a.x, q.x, s); s = fmaf(a.y, q.y, s);
        s = fmaf(a.z, q.z, s); s = fmaf(a.w, q.w, s);
    }
    out[(size_t)(n0 + n) * 1000 + co] = s;
}

// ---------------------------------------------------------------------------
extern "C" void kernel_launch(void* const* d_in, const int* in_sizes, int n_in,
                              void* d_out, int out_size, void* d_ws, size_t ws_size,
                              hipStream_t stream)
{
    (void)n_in; (void)out_size;
    const float* x = (const float*)d_in[0];
    const float* W[7]; const float* Bv[7]; const int* Q[6];
    const bool inter = (in_sizes[2] == 64);
    for (int i = 0; i < 7; ++i) {
        if (inter) { W[i] = (const float*)d_in[1 + 2 * i]; Bv[i] = (const float*)d_in[2 + 2 * i]; }
        else       { W[i] = (const float*)d_in[1 + i];     Bv[i] = (const float*)d_in[8 + i];     }
    }
    for (int i = 0; i < 6; ++i) Q[i] = (const int*)d_in[15 + i];
    const float* fcw = (const float*)d_in[21];
    const float* fcb = (const float*)d_in[22];
    float* outp = (float*)d_out;

    // ---- packed weights at workspace start ----
    static const int FCO[7]  = {64, 64, 128, 128, 256, 256, 256};
    static const int FCIN[7] = {3, 64, 64, 128, 128, 256, 256};
    static const int FTC[7]  = {8, 4, 8, 4, 8, 8, 4};     // convf=8, convfp=4
    static const int QCIN4[6] = {64, 128, 128, 128, 128, 128};
    size_t wfoff[7], wft = 0;
    for (int i = 0; i < 7; ++i) { wfoff[i] = wft; wft += (size_t)FCO[i] * FCIN[i] * 9; }
    size_t wqoff[6], wqt = 0;
    for (int i = 0; i < 6; ++i) { wqoff[i] = wqt; wqt += (size_t)512 * QCIN4[i] * 9 * 4; }
    const size_t WTOT = wft + wqt;

    float* wfb = (float*)d_ws;
    int*   wqb = (int*)((float*)d_ws + wft);
    for (int i = 0; i < 7; ++i) {
        const int total = FCO[i] * FCIN[i] * 9;
        pack_wf_k<<<(total + 255) / 256, 256, 0, stream>>>(W[i], wfb + wfoff[i], FCIN[i], FTC[i], total);
    }
    for (int i = 0; i < 6; ++i) {
        const int total = 512 * QCIN4[i] * 9;
        pack_wq_k<<<(total + 255) / 256, 256, 0, stream>>>(Q[i], wqb + wqoff[i], QCIN4[i], total);
    }

    // ---- arena & per-image tensor sizes (elements) ----
    const long long SZ_X0 = 158688,  SZ_F1 = 3532800, SZ_P1 = 936448;
    const long long SZ_F4 = 2027520, SZ_P2 = 580608,  SZ_F7 = 1264640;
    const long long SZ_F8 = 1440768, SZ_PK1 = 90112;
    const long long SZ_D1 = 168960,  SZ_D2 = 157696,  SZ_D3 = 532480;
    const long long SZ_PK4 = 39936,  SZ_D4 = 33792,   SZ_D5 = 27648;
    const long long SZ_D6 = 86016,   SZ_P5 = 16896;
    const long long DCH = SZ_D1 + SZ_D2 + SZ_D3 + SZ_PK4 + SZ_D4 + SZ_D5 + SZ_D6 + SZ_P5 + 512;

    float* AR = (float*)d_ws + WTOT;
    long long AE2 = ((long long)(ws_size / 4) - (long long)WTOT - 65536) & ~3LL;

    int nbB = 16;
    for (;; nbB >>= 1) {
        if (nbB == 1) break;
        const long long f = nbB;
        const long long low = (nbB == 16) ? 0 : SZ_P1 * 16;
        const bool ok = (SZ_P1 * 16 + SZ_F4 * f <= AE2)
                     && (low + SZ_P2 * f <= AE2 - SZ_F4 * f)
                     && (low + SZ_F8 * f <= AE2 - SZ_F7 * f)
                     && (low + SZ_F8 * f <= AE2 - SZ_PK1 * f)
                     && (low + DCH * f <= AE2 - SZ_PK1 * f);
        if (ok) break;
    }
    int cA = 16;
    while (cA > 1 && SZ_P1 * 16 + (SZ_X0 + SZ_F1) * cA > AE2) cA >>= 1;

    const long long lowb = (nbB == 16) ? 0 : SZ_P1 * 16;
    float* tP1 = AR;
    float* tX0 = AR + SZ_P1 * 16;
    float* tF1 = tX0 + SZ_X0 * cA;
    float* tF4 = AR + (AE2 - SZ_F4 * nbB);
    float* tP2 = AR + lowb;
    float* tF7 = AR + (AE2 - SZ_F7 * nbB);
    float* tF8 = AR + lowb;
    int*   tPK1 = (int*)(AR + (AE2 - SZ_PK1 * nbB));
    int*   tD1 = (int*)(AR + lowb);
    int*   tD2 = tD1 + SZ_D1 * nbB;
    int*   tD3 = tD2 + SZ_D2 * nbB;
    int*   tPK4 = tD3 + SZ_D3 * nbB;
    int*   tD4 = tPK4 + SZ_PK4 * nbB;
    int*   tD5 = tD4 + SZ_D4 * nbB;
    int*   tD6 = tD5 + SZ_D5 * nbB;
    int*   tP5 = tD6 + SZ_D6 * nbB;
    float* tPP = (float*)(tP5 + SZ_P5 * nbB);

    // ---- stage A: copyin, L1, L2+pool -> P1ALL ----
    for (int a0 = 0; a0 < 16; a0 += cA) {
        const int nb = cA;
        {
            const int total = nb * 3 * 228 * 232;
            copyin_k<<<(total + 255) / 256, 256, 0, stream>>>(
                x + (size_t)a0 * 150528, tX0, (int)SZ_X0, total);
        }
        {   // L1: X0 -> F1 (64,230,240) border (direct conv, CIN=3)
            const int total = nb * 226 * 58;
            dim3 g(8, 1, (total + 255) / 256);
            convf_k<3, 228, 232, 226, 230, 240, true><<<g, 256, 0, stream>>>(
                tX0, (int)SZ_X0, wfb + wfoff[0], Bv[0], tF1, (int)SZ_F1, total);
        }
        {   // L2 + pool: F1 -> P1 (64,118,124) border
            const int total = nb * 114 * 59;
            dim3 g(16, 1, (total + 255) / 256);
            convfp_k<64, 230, 240, 114, 118, 124, 2, 2, 0><<<g, 256, 0, stream>>>(
                tF1, (int)SZ_F1, wfb + wfoff[1], Bv[1],
                tP1 + (size_t)a0 * SZ_P1, (int)SZ_P1, total);
        }
    }

    // ---- stage B ----
    for (int b0 = 0; b0 < 16; b0 += nbB) {
        const int nb = nbB;
        {   // L3 (tiled LDS): P1 -> F4 (128,120,132) border; TWB=4,TH=64: WT=8,HT=2
            dim3 g(16, 1, nb * 2 * 8);
            convf_t<64, 118, 124, 116, 122, 132, 4, 64, true><<<g, 256, 0, stream>>>(
                tP1 + (size_t)b0 * SZ_P1, (int)SZ_P1, wfb + wfoff[2], Bv[2],
                tF4, (int)SZ_F4);
        }
        {   // L4 + pool: F4 -> P2 (128,63,72) border
            const int total = nb * 59 * 32;
            dim3 g(32, 1, (total + 255) / 256);
            convfp_k<128, 120, 132, 59, 64, 72, 2, 2, 0><<<g, 256, 0, stream>>>(
                tF4, (int)SZ_F4, wfb + wfoff[3], Bv[3], tP2, (int)SZ_P2, total);
        }
        {   // L5 (tiled LDS): P2 -> F7 (256,65,76) border; WT=5,HT=1
            dim3 g(32, 1, nb * 5);
            convf_t<128, 63, 72, 61, 68, 76, 4, 64, true><<<g, 256, 0, stream>>>(
                tP2, (int)SZ_P2, wfb + wfoff[4], Bv[4], tF7, (int)SZ_F7);
        }
        {   // L6 (tiled LDS): F7 -> F8 (256,67,84) border; WT=5,HT=1
            dim3 g(32, 1, nb * 5);
            convf_t<256, 65, 76, 63, 74, 84, 4, 64, true><<<g, 256, 0, stream>>>(
                tF7, (int)SZ_F7, wfb + wfoff[5], Bv[5], tF8, (int)SZ_F8);
        }
        {   // L7 + pool + int + pack: F8 -> PK1 (64,32,44) i8x4
            const int total = nb * 32 * 20;
            dim3 g(64, 1, (total + 255) / 256);
            convfp_k<256, 67, 84, 32, 40, 44, 0, 0, 1><<<g, 256, 0, stream>>>(
                tF8, (int)SZ_F8, wfb + wfoff[6], Bv[6], (void*)tPK1, (int)SZ_PK1, total);
        }
        {   // D1: PK1 -> D1 packed (128,30,44)
            const int total = nb * 30 * 10;
            dim3 g(64, 1, (total + 255) / 256);
            convq_k<64, 32, 44, 30, 40, 44, true><<<g, 256, 0, stream>>>(
                tPK1, (int)SZ_PK1, wqb + wqoff[0], tD1, (int)SZ_D1, total);
        }
        {   // D2: D1 -> D2 packed (128,28,44)
            const int total = nb * 28 * 10;
            dim3 g(64, 1, (total + 255) / 256);
            convq_k<128, 30, 44, 28, 40, 44, true><<<g, 256, 0, stream>>>(
                tD1, (int)SZ_D1, wqb + wqoff[1], tD2, (int)SZ_D2, total);
        }
        {   // D3: D2 -> D3 raw (512,26,40)
            const int total = nb * 26 * 10;
            dim3 g(64, 1, (total + 255) / 256);
            convq_k<128, 28, 44, 26, 40, 40, false><<<g, 256, 0, stream>>>(
                tD2, (int)SZ_D2, wqb + wqoff[2], tD3, (int)SZ_D3, total);
        }
        {   // P4 fused pool+mask+pack: D3 -> PK4 (128,13,24)
            const int total = nb * 128 * 13 * 24;
            poolpack_k<128, 26, 40, 13, 20, 13, 24><<<(total + 255) / 256, 256, 0, stream>>>(
                tD3, (int)SZ_D3, tPK4, (int)SZ_PK4, total);
        }
        {   // D4: PK4 -> D4 packed (128,11,24)
            const int total = nb * 11 * 6;
            dim3 g(64, 1, (total + 255) / 256);
            convq_k<128, 13, 24, 11, 22, 24, true><<<g, 256, 0, stream>>>(
                tPK4, (int)SZ_PK4, wqb + wqoff[3], tD4, (int)SZ_D4, total);
        }
        {   // D5: D4 -> D5 packed (128,9,24)
            const int total = nb * 9 * 6;
            dim3 g(64, 1, (total + 255) / 256);
            convq_k<128, 11, 24, 9, 22, 24, true><<<g, 256, 0, stream>>>(
                tD4, (int)SZ_D4, wqb + wqoff[4], tD5, (int)SZ_D5, total);
        }
        {   // D6: D5 -> D6 raw (512,7,24)
            const int total = nb * 7 * 6;
            dim3 g(64, 1, (total + 255) / 256);
            convq_k<128, 9, 24, 7, 22, 24, false><<<g, 256, 0, stream>>>(
                tD5, (int)SZ_D5, wqb + wqoff[5], tD6, (int)SZ_D6, total);
        }
        {   // P5: D6 -> P5 (512,3,11)
            const int total = nb * 512 * 33;
            pool_i_k<512, 7, 24, 3, 11, 3, 11><<<(total + 255) / 256, 256, 0, stream>>>(
                tD6, (int)SZ_D6, tP5, (int)SZ_P5, total);
        }
        {   // mean -> PP
            const int total = nb * 512;
            pool_mean_k<<<(total + 255) / 256, 256, 0, stream>>>(
                tP5, (int)SZ_P5, tPP, 512, total);
        }
        {   // FC
            const int total = nb * 1000;
            fc_k<<<(total + 255) / 256, 256, 0, stream>>>(tPP, fcw, fcb, outp, nb, b0);
        }
    }
}

// Round 12
// 5737.147 us; speedup vs baseline: 1.0484x; 1.0484x over previous
//
#include <hip/hip_runtime.h>
#include <cstddef>

// ---------------------------------------------------------------------------
// VGG_DC FINAL (= round 7, measured best 5.79ms): pre-padded arena, fused
// conv+pool (L2/L4/L7), dual-stream row loads feeding v_pk_fma (aligned +
// offset-by-1 so every packed operand is a natural even pair), dot4 DC path
// on i8x4-packed activations, L7 packs i8x4 directly, fused pool+mask+pack,
// float4 FC. Plateau analysis (R5-R11): float convs are VALU-issue-bound at
// ~50% FMA share of busy; weight placement, input staging, cache locality,
// occupancy and per-thread tiling all proven neutral-or-negative.
// ---------------------------------------------------------------------------

typedef float v2f __attribute__((ext_vector_type(2)));

static __device__ __forceinline__ int dot4(int a, int b, int c) {
#if __has_builtin(__builtin_amdgcn_sdot4)
    return __builtin_amdgcn_sdot4(a, b, c, false);
#else
    return c + (a & 255) * (b & 255)
             + ((a >> 8) & 255) * ((b >> 8) & 255)
             + ((a >> 16) & 255) * ((b >> 16) & 255)
             + ((a >> 24) & 255) * ((b >> 24) & 255);
#endif
}

// dual-stream row: a0=[0:1] a1=[2:3] a2=[4:5] (aligned), b0=[1:2] b1=[3:4] (+1)
struct Rw { v2f a0, a1, a2, b0, b1; };

static __device__ __forceinline__ Rw ldr(const float* __restrict__ p) {
    Rw r;
    const float4 x = *reinterpret_cast<const float4*>(p);
    const float2 y = *reinterpret_cast<const float2*>(p + 4);
    const float4 z = *reinterpret_cast<const float4*>(p + 1);
    r.a0 = v2f{x.x, x.y}; r.a1 = v2f{x.z, x.w}; r.a2 = v2f{y.x, y.y};
    r.b0 = v2f{z.x, z.y}; r.b1 = v2f{z.z, z.w};
    return r;
}

static __device__ __forceinline__ void ld6i(const int* __restrict__ p, int v[6]) {
    const int4 a = *reinterpret_cast<const int4*>(p);
    const int2 b = *reinterpret_cast<const int2*>(p + 4);
    v[0] = a.x; v[1] = a.y; v[2] = a.z; v[3] = a.w; v[4] = b.x; v[5] = b.y;
}

// 8 co x 4 w FMA block for one input channel (rows v[0..2])
static __device__ __forceinline__ void fmac8(const Rw v[3],
                                             const float* __restrict__ wr,
                                             v2f acc[8][2])
{
#pragma unroll
    for (int kh = 0; kh < 3; ++kh) {
        const Rw r = v[kh];
#pragma unroll
        for (int c = 0; c < 8; ++c) {
            const float k0 = wr[c * 9 + kh * 3 + 0];
            const float k1 = wr[c * 9 + kh * 3 + 1];
            const float k2 = wr[c * 9 + kh * 3 + 2];
            const v2f k0p = {k0, k0}, k1p = {k1, k1}, k2p = {k2, k2};
            v2f a0 = acc[c][0];
            a0 = __builtin_elementwise_fma(r.a1, k2p, a0);   // P2
            a0 = __builtin_elementwise_fma(r.b0, k1p, a0);   // P1
            a0 = __builtin_elementwise_fma(r.a0, k0p, a0);   // P0
            acc[c][0] = a0;
            v2f a1 = acc[c][1];
            a1 = __builtin_elementwise_fma(r.a2, k2p, a1);   // Q2
            a1 = __builtin_elementwise_fma(r.b1, k1p, a1);   // Q1
            a1 = __builtin_elementwise_fma(r.a1, k0p, a1);   // Q0 (=P2)
            acc[c][1] = a1;
        }
    }
}

// convfp FMA block (4 co, 2 pool-rows x 4 w), rows v[0..3]
static __device__ __forceinline__ void fmac4p(const Rw v[4],
                                              const float* __restrict__ wr,
                                              v2f acc[4][2][2])
{
#pragma unroll
    for (int r = 0; r < 2; ++r) {
#pragma unroll
        for (int kh = 0; kh < 3; ++kh) {
            const Rw rv = v[r + kh];
#pragma unroll
            for (int c = 0; c < 4; ++c) {
                const float k0 = wr[c * 9 + kh * 3 + 0];
                const float k1 = wr[c * 9 + kh * 3 + 1];
                const float k2 = wr[c * 9 + kh * 3 + 2];
                const v2f k0p = {k0, k0}, k1p = {k1, k1}, k2p = {k2, k2};
                v2f a0 = acc[c][r][0];
                a0 = __builtin_elementwise_fma(rv.a1, k2p, a0);
                a0 = __builtin_elementwise_fma(rv.b0, k1p, a0);
                a0 = __builtin_elementwise_fma(rv.a0, k0p, a0);
                acc[c][r][0] = a0;
                v2f a1 = acc[c][r][1];
                a1 = __builtin_elementwise_fma(rv.a2, k2p, a1);
                a1 = __builtin_elementwise_fma(rv.b1, k1p, a1);
                a1 = __builtin_elementwise_fma(rv.a1, k0p, a1);
                acc[c][r][1] = a1;
            }
        }
    }
}

// dot4 block for convq (8 co, 4 w)
static __device__ __forceinline__ void dotc8(const int v[3][6],
                                             const int* __restrict__ wr,
                                             int acc[8][4])
{
#pragma unroll
    for (int kh = 0; kh < 3; ++kh) {
#pragma unroll
        for (int c = 0; c < 8; ++c) {
            const int k0 = wr[c * 9 + kh * 3 + 0];
            const int k1 = wr[c * 9 + kh * 3 + 1];
            const int k2 = wr[c * 9 + kh * 3 + 2];
#pragma unroll
            for (int t = 0; t < 4; ++t)
                acc[c][t] = dot4(v[kh][t], k0,
                            dot4(v[kh][t + 1], k1,
                            dot4(v[kh][t + 2], k2, acc[c][t])));
        }
    }
}

// ---- fp32 conv3x3 over pre-padded input, 8 co x 4 w per thread -----------
// grid: x = co-block, z = spatial chunk
template<int CIN,int PH,int PW,int OH,int OW,int OPW,bool BORDER>
__global__ __launch_bounds__(256) void convf_k(
    const float* __restrict__ in, int instr,
    const float* __restrict__ wfp, const float* __restrict__ bias,
    float* __restrict__ out, int outstr, int total)
{
    constexpr int WB  = (OW + 3) / 4;
    constexpr int OPH = BORDER ? OH + 4 : OH;
    constexpr int OPL = OPH * OPW;
    const int s = blockIdx.z * 256 + threadIdx.x;
    if (s >= total) return;
    const int wb = s % WB;
    const int h  = (s / WB) % OH;
    const int n  = s / (WB * OH);
    const int w0 = wb * 4;
    const int cob = blockIdx.x;
    const int co0 = cob * 8;

    const float* ip = in + (size_t)n * instr + (size_t)h * PW + w0;
    const float* wl = wfp + (size_t)cob * CIN * 72;

    v2f acc[8][2];
#pragma unroll
    for (int c = 0; c < 8; ++c) { acc[c][0] = (v2f)0.f; acc[c][1] = (v2f)0.f; }

#pragma unroll 2
    for (int ci = 0; ci < CIN; ++ci) {
        Rw v[3];
#pragma unroll
        for (int kh = 0; kh < 3; ++kh) v[kh] = ldr(ip + kh * PW);
        fmac8(v, wl + (size_t)ci * 72, acc);
        ip += PH * PW;
    }

    float* ob = out + (size_t)n * outstr;
    const int ph  = BORDER ? h + 2 : h;
    const int pwo = BORDER ? 2 : 0;
#pragma unroll
    for (int c = 0; c < 8; ++c) {
        float* plane = ob + (size_t)(co0 + c) * OPL;
        float* row = plane + (size_t)ph * OPW;
        const float b = bias[co0 + c];
        const float av[4] = {acc[c][0][0], acc[c][0][1], acc[c][1][0], acc[c][1][1]};
#pragma unroll
        for (int t = 0; t < 4; ++t)
            if (w0 + t < OW) { const float r = av[t] + b; row[pwo + w0 + t] = r > 0.f ? r : 0.f; }
        if (BORDER) {
            if (wb == 0) { row[0] = 0.f; row[1] = 0.f; }
            if (wb == WB - 1) { for (int pw = OW + 2; pw < OPW; ++pw) row[pw] = 0.f; }
            if (h == 0 || h == OH - 1) {
                float* r0 = plane + (h == 0 ? 0 : (size_t)(OH + 2) * OPW);
                for (int rr = 0; rr < 2; ++rr) {
                    float* br = r0 + (size_t)rr * OPW;
#pragma unroll
                    for (int t = 0; t < 4; ++t) if (w0 + t < OW) br[2 + w0 + t] = 0.f;
                    if (wb == 0) { br[0] = 0.f; br[1] = 0.f; }
                    if (wb == WB - 1) { for (int pw = OW + 2; pw < OPW; ++pw) br[pw] = 0.f; }
                }
            }
        }
    }
}

// ---- fused fp32 conv3x3 + relu + maxpool2; MODE 0=float out, 1=packed i8x4
template<int CIN,int PH,int PW,int POH,int POW,int OPW,int OY,int OX,int MODE>
__global__ __launch_bounds__(256) void convfp_k(
    const float* __restrict__ in, int instr,
    const float* __restrict__ wfp, const float* __restrict__ bias,
    void* __restrict__ outv, int outstr, int total)
{
    constexpr int WBp = POW / 2;
    constexpr int OPH = POH + 2 * OY;
    constexpr int OPL = OPH * OPW;
    const int s = blockIdx.z * 256 + threadIdx.x;
    if (s >= total) return;
    const int pb = s % WBp;
    const int ph = (s / WBp) % POH;
    const int n  = s / (WBp * POH);
    const int cob = blockIdx.x;
    const int co0 = cob * 4;

    const float* ip = in + (size_t)n * instr + (size_t)(2 * ph) * PW + 4 * pb;
    const float* wl = wfp + (size_t)cob * CIN * 36;

    v2f acc[4][2][2];
#pragma unroll
    for (int c = 0; c < 4; ++c)
#pragma unroll
        for (int r = 0; r < 2; ++r) { acc[c][r][0] = (v2f)0.f; acc[c][r][1] = (v2f)0.f; }

#pragma unroll 2
    for (int ci = 0; ci < CIN; ++ci) {
        Rw v[4];
#pragma unroll
        for (int r = 0; r < 4; ++r) v[r] = ldr(ip + r * PW);
        fmac4p(v, wl + (size_t)ci * 36, acc);
        ip += PH * PW;
    }

    float p[4][2];
#pragma unroll
    for (int c = 0; c < 4; ++c) {
        const float b = bias[co0 + c];
        float r00 = acc[c][0][0][0] + b; r00 = r00 > 0.f ? r00 : 0.f;
        float r01 = acc[c][0][0][1] + b; r01 = r01 > 0.f ? r01 : 0.f;
        float r02 = acc[c][0][1][0] + b; r02 = r02 > 0.f ? r02 : 0.f;
        float r03 = acc[c][0][1][1] + b; r03 = r03 > 0.f ? r03 : 0.f;
        float r10 = acc[c][1][0][0] + b; r10 = r10 > 0.f ? r10 : 0.f;
        float r11 = acc[c][1][0][1] + b; r11 = r11 > 0.f ? r11 : 0.f;
        float r12 = acc[c][1][1][0] + b; r12 = r12 > 0.f ? r12 : 0.f;
        float r13 = acc[c][1][1][1] + b; r13 = r13 > 0.f ? r13 : 0.f;
        float p0 = r00; p0 = p0 > r01 ? p0 : r01; p0 = p0 > r10 ? p0 : r10; p0 = p0 > r11 ? p0 : r11;
        float p1 = r02; p1 = p1 > r03 ? p1 : r03; p1 = p1 > r12 ? p1 : r12; p1 = p1 > r13 ? p1 : r13;
        p[c][0] = p0; p[c][1] = p1;
    }

    if constexpr (MODE == 1) {
        int* base = (int*)outv + (size_t)n * outstr + (size_t)cob * OPL
                  + (size_t)(OY + ph) * OPW + OX + 2 * pb;
        base[0] = (((int)p[0][0]) & 31) | ((((int)p[1][0]) & 31) << 8)
                | ((((int)p[2][0]) & 31) << 16) | ((((int)p[3][0]) & 31) << 24);
        base[1] = (((int)p[0][1]) & 31) | ((((int)p[1][1]) & 31) << 8)
                | ((((int)p[2][1]) & 31) << 16) | ((((int)p[3][1]) & 31) << 24);
        if (pb == WBp - 1) {
            int* row = (int*)outv + (size_t)n * outstr + (size_t)cob * OPL
                     + (size_t)(OY + ph) * OPW;
            for (int pw = OX + POW; pw < OPW; ++pw) row[pw] = 0;
        }
    } else {
#pragma unroll
        for (int c = 0; c < 4; ++c) {
            float* plane = (float*)outv + (size_t)n * outstr + (size_t)(co0 + c) * OPL;
            float* row = plane + (size_t)(OY + ph) * OPW;
            row[OX + 2 * pb]     = p[c][0];
            row[OX + 2 * pb + 1] = p[c][1];
            if (OX > 0 && pb == 0) { row[0] = 0.f; row[1] = 0.f; }
            if (pb == WBp - 1) { for (int pw = OX + POW; pw < OPW; ++pw) row[pw] = 0.f; }
            if (OY > 0 && (ph == 0 || ph == POH - 1)) {
                float* r0 = plane + (ph == 0 ? 0 : (size_t)(OY + POH) * OPW);
                for (int rr = 0; rr < OY; ++rr) {
                    float* br = r0 + (size_t)rr * OPW;
                    br[OX + 2 * pb] = 0.f; br[OX + 2 * pb + 1] = 0.f;
                    if (pb == 0) { br[0] = 0.f; br[1] = 0.f; }
                    if (pb == WBp - 1) { for (int pw = OX + POW; pw < OPW; ++pw) br[pw] = 0.f; }
                }
            }
        }
    }
}

// ---- int DC conv3x3 (valid) on i8x4-packed input -------------------------
template<int CIN4,int PH,int PW,int OH,int OW,int OPW,bool PACKOUT>
__global__ __launch_bounds__(256) void convq_k(
    const int* __restrict__ in, int instr, const int* __restrict__ wqp,
    int* __restrict__ out, int outstr, int total)
{
    constexpr int WB  = (OW + 3) / 4;
    constexpr int OPL = OH * OPW;
    const int s = blockIdx.z * 256 + threadIdx.x;
    if (s >= total) return;
    const int wb = s % WB;
    const int h  = (s / WB) % OH;
    const int n  = s / (WB * OH);
    const int w0 = wb * 4;
    const int cob = blockIdx.x;
    const int co0 = cob * 8;

    const int* ip = in + (size_t)n * instr + (size_t)h * PW + w0;
    const int* wl = wqp + (size_t)cob * CIN4 * 72;

    int acc[8][4];
#pragma unroll
    for (int c = 0; c < 8; ++c)
#pragma unroll
        for (int t = 0; t < 4; ++t) acc[c][t] = 0;

    int vb[3][6], vn[3][6];
#pragma unroll
    for (int kh = 0; kh < 3; ++kh) ld6i(ip + kh * PW, vb[kh]);

    for (int ci = 0; ci < CIN4; ci += 2) {       // CIN4 even always
        ip += PH * PW;
#pragma unroll
        for (int kh = 0; kh < 3; ++kh) ld6i(ip + kh * PW, vn[kh]);
        dotc8(vb, wl + (size_t)ci * 72, acc);
        ip += PH * PW;                           // final iter overreads 1 plane (guarded)
#pragma unroll
        for (int kh = 0; kh < 3; ++kh) ld6i(ip + kh * PW, vb[kh]);
        dotc8(vn, wl + (size_t)(ci + 1) * 72, acc);
    }

    if (PACKOUT) {
        int* base = out + (size_t)n * outstr + (size_t)(cob * 2) * OPL + (size_t)h * OPW + w0;
#pragma unroll
        for (int t = 0; t < 4; ++t) {
            if (w0 + t < OW) {
                const int lo = (acc[0][t] & 31) | ((acc[1][t] & 31) << 8)
                             | ((acc[2][t] & 31) << 16) | ((acc[3][t] & 31) << 24);
                const int hi = (acc[4][t] & 31) | ((acc[5][t] & 31) << 8)
                             | ((acc[6][t] & 31) << 16) | ((acc[7][t] & 31) << 24);
                base[t] = lo;
                base[OPL + t] = hi;
            }
        }
        if (wb == WB - 1) {
            for (int pw = OW; pw < OPW; ++pw) { base[pw - w0] = 0; base[OPL + pw - w0] = 0; }
        }
    } else {
        int* ob = out + (size_t)n * outstr;
#pragma unroll
        for (int c = 0; c < 8; ++c) {
            int* row = ob + (size_t)(co0 + c) * OPL + (size_t)h * OPW;
#pragma unroll
            for (int t = 0; t < 4; ++t)
                if (w0 + t < OW) row[w0 + t] = acc[c][t];
            if (wb == WB - 1) { for (int pw = OW; pw < OPW; ++pw) row[pw] = 0; }
        }
    }
}

// ---- weight packing ------------------------------------------------------
__global__ void pack_wf_k(const float* __restrict__ w, float* __restrict__ out,
                          int CIN, int TC, int total)
{
    const int i = blockIdx.x * 256 + threadIdx.x;
    if (i >= total) return;
    const int r = i % 9;
    const int c = (i / 9) % TC;
    const int t = i / (9 * TC);
    const int ci = t % CIN;
    const int cob = t / CIN;
    out[i] = w[(((size_t)cob * TC + c) * CIN + ci) * 9 + r];
}

__global__ void pack_wq_k(const int* __restrict__ q, int* __restrict__ out,
                          int CIN4, int total)
{
    const int i = blockIdx.x * 256 + threadIdx.x;
    if (i >= total) return;
    const int r = i % 9;
    const int c = (i / 9) % 8;
    const int t = i / 72;
    const int ci4 = t % CIN4;
    const int cob = t / CIN4;
    const int co = cob * 8 + c;
    const int* p = q + ((size_t)co * CIN4 * 4 + ci4 * 4) * 9 + r;
    out[i] = (p[0] & 255) | ((p[9] & 255) << 8) | ((p[18] & 255) << 16) | ((p[27] & 255) << 24);
}

// ---- fused int maxpool 2x2/2 + mask + i8x4 pack --------------------------
template<int C4,int HI,int WI,int HO,int WO,int OPH,int OPW>
__global__ void poolpack_k(const int* __restrict__ in, int instr,
                           int* __restrict__ out, int outstr, int total)
{
    const int i = blockIdx.x * 256 + threadIdx.x;
    if (i >= total) return;
    int t = i;
    const int px = t % OPW; t /= OPW;
    const int py = t % OPH; t /= OPH;
    const int c4 = t % C4;  const int n = t / C4;
    int word = 0;
    if (py < HO && px < WO) {
#pragma unroll
        for (int j = 0; j < 4; ++j) {
            const int* p = in + (size_t)n * instr
                         + ((size_t)(c4 * 4 + j) * HI + 2 * py) * WI + 2 * px;
            int m = p[0];
            m = m > p[1] ? m : p[1];
            m = m > p[WI] ? m : p[WI];
            m = m > p[WI + 1] ? m : p[WI + 1];
            word |= (m & 31) << (8 * j);
        }
    }
    out[(size_t)n * outstr + ((size_t)c4 * OPH + py) * OPW + px] = word;
}

// ---- int maxpool (raw) ---------------------------------------------------
template<int C,int HI,int WI,int HO,int WO,int OPH,int OPW>
__global__ void pool_i_k(const int* __restrict__ in, int instr,
                         int* __restrict__ out, int outstr, int total)
{
    const int i = blockIdx.x * 256 + threadIdx.x;
    if (i >= total) return;
    constexpr int OPL = OPH * OPW;
    int t = i;
    const int px = t % OPW; t /= OPW;
    const int py = t % OPH; t /= OPH;
    const int c  = t % C;   const int n = t / C;
    int v = 0;
    if (py < HO && px < WO) {
        const int* p = in + (size_t)n * instr + ((size_t)c * HI + 2 * py) * WI + 2 * px;
        int m = p[0];
        m = m > p[1] ? m : p[1];
        m = m > p[WI] ? m : p[WI];
        m = m > p[WI + 1] ? m : p[WI + 1];
        v = m;
    }
    out[(size_t)n * outstr + (size_t)c * OPL + (size_t)py * OPW + px] = v;
}

// ---- copy x into padded (3,228,232) --------------------------------------
__global__ void copyin_k(const float* __restrict__ x, float* __restrict__ dst,
                         int outstr, int total)
{
    const int i = blockIdx.x * 256 + threadIdx.x;
    if (i >= total) return;
    int t = i;
    const int pw = t % 232; t /= 232;
    const int ph = t % 228; t /= 228;
    const int c  = t % 3;   const int n = t / 3;
    float v = 0.f;
    const int y = ph - 2, xx = pw - 2;
    if ((unsigned)y < 224u && (unsigned)xx < 224u)
        v = x[(size_t)n * 150528 + ((size_t)c * 224 + y) * 224 + xx];
    dst[(size_t)n * outstr + ((size_t)c * 228 + ph) * 232 + pw] = v;
}

// ---- head ----------------------------------------------------------------
__global__ void pool_mean_k(const int* __restrict__ in, int instr,
                            float* __restrict__ out, int outstr, int total)
{
    const int i = blockIdx.x * 256 + threadIdx.x;
    if (i >= total) return;
    const int n = i / 512, c = i % 512;
    const int* p = in + (size_t)n * instr + (size_t)c * 33;
    int s = 0;
#pragma unroll
    for (int j = 0; j < 33; ++j) s += p[j];
    out[(size_t)n * outstr + c] = (float)s / 33.0f;
}

__global__ void fc_k(const float* __restrict__ pooled, const float* __restrict__ w,
                     const float* __restrict__ b, float* __restrict__ out,
                     int nb, int n0)
{
    const int i = blockIdx.x * 256 + threadIdx.x;
    if (i >= nb * 1000) return;
    const int co = i % 1000;
    const int n  = i / 1000;
    const float4* pv = (const float4*)(pooled + (size_t)n * 512);
    const float4* wr = (const float4*)(w + (size_t)co * 512);
    float s = b[co];
    for (int c = 0; c < 128; ++c) {
        const float4 a = pv[c], q = wr[c];
        s = fmaf(a.x, q.x, s); s = fmaf(a.y, q.y, s);
        s = fmaf(a.z, q.z, s); s = fmaf(a.w, q.w, s);
    }
    out[(size_t)(n0 + n) * 1000 + co] = s;
}

// ---------------------------------------------------------------------------
extern "C" void kernel_launch(void* const* d_in, const int* in_sizes, int n_in,
                              void* d_out, int out_size, void* d_ws, size_t ws_size,
                              hipStream_t stream)
{
    (void)n_in; (void)out_size;
    const float* x = (const float*)d_in[0];
    const float* W[7]; const float* Bv[7]; const int* Q[6];
    const bool inter = (in_sizes[2] == 64);
    for (int i = 0; i < 7; ++i) {
        if (inter) { W[i] = (const float*)d_in[1 + 2 * i]; Bv[i] = (const float*)d_in[2 + 2 * i]; }
        else       { W[i] = (const float*)d_in[1 + i];     Bv[i] = (const float*)d_in[8 + i];     }
    }
    for (int i = 0; i < 6; ++i) Q[i] = (const int*)d_in[15 + i];
    const float* fcw = (const float*)d_in[21];
    const float* fcb = (const float*)d_in[22];
    float* outp = (float*)d_out;

    // ---- packed weights at workspace start ----
    static const int FCO[7]  = {64, 64, 128, 128, 256, 256, 256};
    static const int FCIN[7] = {3, 64, 64, 128, 128, 256, 256};
    static const int FTC[7]  = {8, 4, 8, 4, 8, 8, 4};     // convf=8, convfp=4
    static const int QCIN4[6] = {64, 128, 128, 128, 128, 128};
    size_t wfoff[7], wft = 0;
    for (int i = 0; i < 7; ++i) { wfoff[i] = wft; wft += (size_t)FCO[i] * FCIN[i] * 9; }
    size_t wqoff[6], wqt = 0;
    for (int i = 0; i < 6; ++i) { wqoff[i] = wqt; wqt += (size_t)512 * QCIN4[i] * 9 * 4; }
    const size_t WTOT = wft + wqt;

    float* wfb = (float*)d_ws;
    int*   wqb = (int*)((float*)d_ws + wft);
    for (int i = 0; i < 7; ++i) {
        const int total = FCO[i] * FCIN[i] * 9;
        pack_wf_k<<<(total + 255) / 256, 256, 0, stream>>>(W[i], wfb + wfoff[i], FCIN[i], FTC[i], total);
    }
    for (int i = 0; i < 6; ++i) {
        const int total = 512 * QCIN4[i] * 9;
        pack_wq_k<<<(total + 255) / 256, 256, 0, stream>>>(Q[i], wqb + wqoff[i], QCIN4[i], total);
    }

    // ---- arena & per-image tensor sizes (elements) ----
    const long long SZ_X0 = 158688,  SZ_F1 = 3532800, SZ_P1 = 936448;
    const long long SZ_F4 = 2027520, SZ_P2 = 580608,  SZ_F7 = 1264640;
    const long long SZ_F8 = 1440768, SZ_PK1 = 90112;
    const long long SZ_D1 = 168960,  SZ_D2 = 157696,  SZ_D3 = 532480;
    const long long SZ_PK4 = 39936,  SZ_D4 = 33792,   SZ_D5 = 27648;
    const long long SZ_D6 = 86016,   SZ_P5 = 16896;
    const long long DCH = SZ_D1 + SZ_D2 + SZ_D3 + SZ_PK4 + SZ_D4 + SZ_D5 + SZ_D6 + SZ_P5 + 512;

    float* AR = (float*)d_ws + WTOT;
    long long AE2 = ((long long)(ws_size / 4) - (long long)WTOT - 65536) & ~3LL;

    int nbB = 16;
    for (;; nbB >>= 1) {
        if (nbB == 1) break;
        const long long f = nbB;
        const long long low = (nbB == 16) ? 0 : SZ_P1 * 16;
        const bool ok = (SZ_P1 * 16 + SZ_F4 * f <= AE2)
                     && (low + SZ_P2 * f <= AE2 - SZ_F4 * f)
                     && (low + SZ_F8 * f <= AE2 - SZ_F7 * f)
                     && (low + SZ_F8 * f <= AE2 - SZ_PK1 * f)
                     && (low + DCH * f <= AE2 - SZ_PK1 * f);
        if (ok) break;
    }
    int cA = 16;
    while (cA > 1 && SZ_P1 * 16 + (SZ_X0 + SZ_F1) * cA > AE2) cA >>= 1;

    const long long lowb = (nbB == 16) ? 0 : SZ_P1 * 16;
    float* tP1 = AR;
    float* tX0 = AR + SZ_P1 * 16;
    float* tF1 = tX0 + SZ_X0 * cA;
    float* tF4 = AR + (AE2 - SZ_F4 * nbB);
    float* tP2 = AR + lowb;
    float* tF7 = AR + (AE2 - SZ_F7 * nbB);
    float* tF8 = AR + lowb;
    int*   tPK1 = (int*)(AR + (AE2 - SZ_PK1 * nbB));
    int*   tD1 = (int*)(AR + lowb);
    int*   tD2 = tD1 + SZ_D1 * nbB;
    int*   tD3 = tD2 + SZ_D2 * nbB;
    int*   tPK4 = tD3 + SZ_D3 * nbB;
    int*   tD4 = tPK4 + SZ_PK4 * nbB;
    int*   tD5 = tD4 + SZ_D4 * nbB;
    int*   tD6 = tD5 + SZ_D5 * nbB;
    int*   tP5 = tD6 + SZ_D6 * nbB;
    float* tPP = (float*)(tP5 + SZ_P5 * nbB);

    // ---- stage A: copyin, L1, L2+pool -> P1ALL ----
    for (int a0 = 0; a0 < 16; a0 += cA) {
        const int nb = cA;
        {
            const int total = nb * 3 * 228 * 232;
            copyin_k<<<(total + 255) / 256, 256, 0, stream>>>(
                x + (size_t)a0 * 150528, tX0, (int)SZ_X0, total);
        }
        {   // L1: X0 -> F1 (64,230,240) border
            const int total = nb * 226 * 58;
            dim3 g(8, 1, (total + 255) / 256);
            convf_k<3, 228, 232, 226, 230, 240, true><<<g, 256, 0, stream>>>(
                tX0, (int)SZ_X0, wfb + wfoff[0], Bv[0], tF1, (int)SZ_F1, total);
        }
        {   // L2 + pool: F1 -> P1 (64,118,124) border
            const int total = nb * 114 * 59;
            dim3 g(16, 1, (total + 255) / 256);
            convfp_k<64, 230, 240, 114, 118, 124, 2, 2, 0><<<g, 256, 0, stream>>>(
                tF1, (int)SZ_F1, wfb + wfoff[1], Bv[1],
                tP1 + (size_t)a0 * SZ_P1, (int)SZ_P1, total);
        }
    }

    // ---- stage B ----
    for (int b0 = 0; b0 < 16; b0 += nbB) {
        const int nb = nbB;
        {   // L3: P1 -> F4 (128,120,132) border
            const int total = nb * 116 * 31;
            dim3 g(16, 1, (total + 255) / 256);
            convf_k<64, 118, 124, 116, 122, 132, true><<<g, 256, 0, stream>>>(
                tP1 + (size_t)b0 * SZ_P1, (int)SZ_P1, wfb + wfoff[2], Bv[2],
                tF4, (int)SZ_F4, total);
        }
        {   // L4 + pool: F4 -> P2 (128,63,72) border
            const int total = nb * 59 * 32;
            dim3 g(32, 1, (total + 255) / 256);
            convfp_k<128, 120, 132, 59, 64, 72, 2, 2, 0><<<g, 256, 0, stream>>>(
                tF4, (int)SZ_F4, wfb + wfoff[3], Bv[3], tP2, (int)SZ_P2, total);
        }
        {   // L5: P2 -> F7 (256,65,76) border
            const int total = nb * 61 * 17;
            dim3 g(32, 1, (total + 255) / 256);
            convf_k<128, 63, 72, 61, 68, 76, true><<<g, 256, 0, stream>>>(
                tP2, (int)SZ_P2, wfb + wfoff[4], Bv[4], tF7, (int)SZ_F7, total);
        }
        {   // L6: F7 -> F8 (256,67,84) border
            const int total = nb * 63 * 19;
            dim3 g(32, 1, (total + 255) / 256);
            convf_k<256, 65, 76, 63, 74, 84, true><<<g, 256, 0, stream>>>(
                tF7, (int)SZ_F7, wfb + wfoff[5], Bv[5], tF8, (int)SZ_F8, total);
        }
        {   // L7 + pool + int + pack: F8 -> PK1 (64,32,44) i8x4
            const int total = nb * 32 * 20;
            dim3 g(64, 1, (total + 255) / 256);
            convfp_k<256, 67, 84, 32, 40, 44, 0, 0, 1><<<g, 256, 0, stream>>>(
                tF8, (int)SZ_F8, wfb + wfoff[6], Bv[6], (void*)tPK1, (int)SZ_PK1, total);
        }
        {   // D1: PK1 -> D1 packed (128,30,44)
            const int total = nb * 30 * 10;
            dim3 g(64, 1, (total + 255) / 256);
            convq_k<64, 32, 44, 30, 40, 44, true><<<g, 256, 0, stream>>>(
                tPK1, (int)SZ_PK1, wqb + wqoff[0], tD1, (int)SZ_D1, total);
        }
        {   // D2: D1 -> D2 packed (128,28,44)
            const int total = nb * 28 * 10;
            dim3 g(64, 1, (total + 255) / 256);
            convq_k<128, 30, 44, 28, 40, 44, true><<<g, 256, 0, stream>>>(
                tD1, (int)SZ_D1, wqb + wqoff[1], tD2, (int)SZ_D2, total);
        }
        {   // D3: D2 -> D3 raw (512,26,40)
            const int total = nb * 26 * 10;
            dim3 g(64, 1, (total + 255) / 256);
            convq_k<128, 28, 44, 26, 40, 40, false><<<g, 256, 0, stream>>>(
                tD2, (int)SZ_D2, wqb + wqoff[2], tD3, (int)SZ_D3, total);
        }
        {   // P4 fused pool+mask+pack: D3 -> PK4 (128,13,24)
            const int total = nb * 128 * 13 * 24;
            poolpack_k<128, 26, 40, 13, 20, 13, 24><<<(total + 255) / 256, 256, 0, stream>>>(
                tD3, (int)SZ_D3, tPK4, (int)SZ_PK4, total);
        }
        {   // D4: PK4 -> D4 packed (128,11,24)
            const int total = nb * 11 * 6;
            dim3 g(64, 1, (total + 255) / 256);
            convq_k<128, 13, 24, 11, 22, 24, true><<<g, 256, 0, stream>>>(
                tPK4, (int)SZ_PK4, wqb + wqoff[3], tD4, (int)SZ_D4, total);
        }
        {   // D5: D4 -> D5 packed (128,9,24)
            const int total = nb * 9 * 6;
            dim3 g(64, 1, (total + 255) / 256);
            convq_k<128, 11, 24, 9, 22, 24, true><<<g, 256, 0, stream>>>(
                tD4, (int)SZ_D4, wqb + wqoff[4], tD5, (int)SZ_D5, total);
        }
        {   // D6: D5 -> D6 raw (512,7,24)
            const int total = nb * 7 * 6;
            dim3 g(64, 1, (total + 255) / 256);
            convq_k<128, 9, 24, 7, 22, 24, false><<<g, 256, 0, stream>>>(
                tD5, (int)SZ_D5, wqb + wqoff[5], tD6, (int)SZ_D6, total);
        }
        {   // P5: D6 -> P5 (512,3,11)
            const int total = nb * 512 * 33;
            pool_i_k<512, 7, 24, 3, 11, 3, 11><<<(total + 255) / 256, 256, 0, stream>>>(
                tD6, (int)SZ_D6, tP5, (int)SZ_P5, total);
        }
        {   // mean -> PP
            const int total = nb * 512;
            pool_mean_k<<<(total + 255) / 256, 256, 0, stream>>>(
                tP5, (int)SZ_P5, tPP, 512, total);
        }
        {   // FC
            const int total = nb * 1000;
            fc_k<<<(total + 255) / 256, 256, 0, stream>>>(tPP, fcw, fcb, outp, nb, b0);
        }
    }
}